// Round 5
// baseline (800.625 us; speedup 1.0000x reference)
//
#include <hip/hip_runtime.h>
#include <math.h>
#include <stdint.h>

#define N_NODES 50000
#define N_EDGES 800000
#define EDGE_BLOCKS 1250
#define TILES_PER_BLOCK 5      // 1250 * 5 * 128 = 800000 edges
#define NCHUNK 256
#define CHN 196                // 256*196 = 50176 >= 50000

#define GEMM_BLOCKS 2346       // 782 * 3
#define BPREP_BLOCKS 8
#define HIST_BLOCKS 3125

typedef __attribute__((ext_vector_type(8))) short short8;   // 8 bf16 (4 VGPRs)
typedef __attribute__((ext_vector_type(4))) float f32x4;

__device__ inline unsigned short bf16_rne(float x) {
    unsigned u = __float_as_uint(x);
    unsigned r = u + 0x7FFFu + ((u >> 16) & 1u);
    return (unsigned short)(r >> 16);
}
__device__ inline float bf16_to_f32(unsigned short h) {
    return __uint_as_float(((unsigned)h) << 16);
}

// ---------------- K_A: fused prep  (node GEMM | We-frag prep | dst hist) ---
__global__ __launch_bounds__(256) void prep_kernel(
    const float* __restrict__ x,
    const float* __restrict__ Wq, const float* __restrict__ bq,
    const float* __restrict__ Wk, const float* __restrict__ bk,
    const float* __restrict__ Wv, const float* __restrict__ bv,
    const float* __restrict__ We,
    const int*   __restrict__ edge_index,
    float* __restrict__ Qo, float* __restrict__ Ko, float* __restrict__ Vo,
    unsigned short* __restrict__ Bg, int* __restrict__ counts)
{
    const int b = blockIdx.x;
    const int t = threadIdx.x;

    if (b >= GEMM_BLOCKS + BPREP_BLOCKS) {            // ---- hist ----
        int e = (b - GEMM_BLOCKS - BPREP_BLOCKS) * 256 + t;
        if (e < N_EDGES) atomicAdd(&counts[edge_index[N_EDGES + e]], 1);
        return;
    }
    if (b >= GEMM_BLOCKS) {                           // ---- bprep ----
        int tid = (b - GEMM_BLOCKS) * 256 + t;        // 2048 threads
        int k  = tid >> 5;
        int n4 = (tid & 31) * 4;
        float4 v4 = *(const float4*)&We[(size_t)k * 128 + n4];
        int c = k >> 5, qq = (k >> 3) & 3, jj = k & 7;
        float vv[4] = {v4.x, v4.y, v4.z, v4.w};
        #pragma unroll
        for (int u = 0; u < 4; u++) {
            int nn = n4 + u;
            int j  = nn >> 4;
            int ln = qq * 16 + (nn & 15);
            unsigned short hi = bf16_rne(vv[u]);
            unsigned short lo = bf16_rne(vv[u] - bf16_to_f32(hi));
            Bg[(j * 2 + c) * 512 + ln * 8 + jj] = hi;           // hi half
            Bg[8192 + (j * 2 + c) * 512 + ln * 8 + jj] = lo;    // lo half
        }
        return;
    }

    // ---- node GEMM  X(N x 64) @ W(64 x 64) + b ----
    const int c  = b / 782;
    const int bx = b - c * 782;
    const float* W = (c == 0) ? Wq : (c == 1) ? Wk : Wv;
    const float* bb_ = (c == 0) ? bq : (c == 1) ? bk : bv;
    float* outp    = (c == 0) ? Qo : (c == 1) ? Ko : Vo;

    __shared__ float Xs[64][68];
    __shared__ float Ws[64][64];
    const int n0 = bx * 64;

    for (int i = 0; i < 4; i++) {
        int fi = t + i * 256;
        int row = fi >> 4, c4 = (fi & 15) * 4;
        float4 v = make_float4(0.f, 0.f, 0.f, 0.f);
        if (n0 + row < N_NODES) v = *(const float4*)&x[(size_t)(n0 + row) * 64 + c4];
        *(float4*)&Xs[row][c4] = v;
    }
    for (int i = 0; i < 4; i++) {
        int fi = t + i * 256;
        int row = fi >> 4, c4 = (fi & 15) * 4;
        *(float4*)&Ws[row][c4] = *(const float4*)&W[(size_t)row * 64 + c4];
    }
    __syncthreads();

    const int tx = t & 15, ty = t >> 4;
    float acc[4][4] = {};
    #pragma unroll
    for (int k4 = 0; k4 < 64; k4 += 4) {
        float4 xv[4], wv[4];
        #pragma unroll
        for (int r = 0; r < 4; r++) xv[r] = *(const float4*)&Xs[ty * 4 + r][k4];
        #pragma unroll
        for (int j = 0; j < 4; j++) wv[j] = *(const float4*)&Ws[k4 + j][tx * 4];
        #pragma unroll
        for (int r = 0; r < 4; r++) {
            acc[r][0] += xv[r].x * wv[0].x + xv[r].y * wv[1].x + xv[r].z * wv[2].x + xv[r].w * wv[3].x;
            acc[r][1] += xv[r].x * wv[0].y + xv[r].y * wv[1].y + xv[r].z * wv[2].y + xv[r].w * wv[3].y;
            acc[r][2] += xv[r].x * wv[0].z + xv[r].y * wv[1].z + xv[r].z * wv[2].z + xv[r].w * wv[3].z;
            acc[r][3] += xv[r].x * wv[0].w + xv[r].y * wv[1].w + xv[r].z * wv[2].w + xv[r].w * wv[3].w;
        }
    }
    float4 bv4 = *(const float4*)&bb_[tx * 4];
    #pragma unroll
    for (int r = 0; r < 4; r++) {
        int row = n0 + ty * 4 + r;
        if (row < N_NODES) {
            float4 o;
            o.x = acc[r][0] + bv4.x; o.y = acc[r][1] + bv4.y;
            o.z = acc[r][2] + bv4.z; o.w = acc[r][3] + bv4.w;
            *(float4*)&outp[(size_t)row * 64 + tx * 4] = o;
        }
    }
}

// ---------------- parallel scan (2 kernels) --------------------------------
__global__ __launch_bounds__(256) void chunk_reduce_kernel(
    const int* __restrict__ counts, int* __restrict__ chunksum)
{
    __shared__ int red[256];
    const int c = blockIdx.x, t = threadIdx.x;
    int idx = c * CHN + t;
    int v = (t < CHN && idx < N_NODES) ? counts[idx] : 0;
    red[t] = v;
    __syncthreads();
    for (int s = 128; s > 0; s >>= 1) {
        if (t < s) red[t] += red[t + s];
        __syncthreads();
    }
    if (t == 0) chunksum[c] = red[0];
}

__global__ __launch_bounds__(256) void expand_kernel(
    const int* __restrict__ counts, const int* __restrict__ chunksum,
    int* __restrict__ cursor)
{
    __shared__ int shc[256];
    __shared__ int sh[256];
    const int c = blockIdx.x, t = threadIdx.x;
    shc[t] = chunksum[t];
    __syncthreads();
    for (int off = 1; off < 256; off <<= 1) {
        int v = (t >= off) ? shc[t - off] : 0;
        __syncthreads();
        shc[t] += v;
        __syncthreads();
    }
    int co = (c > 0) ? shc[c - 1] : 0;           // exclusive chunk offset

    int idx = c * CHN + t;
    int own = (t < CHN && idx < N_NODES) ? counts[idx] : 0;
    sh[t] = own;
    __syncthreads();
    for (int off = 1; off < 256; off <<= 1) {
        int v = (t >= off) ? sh[t - off] : 0;
        __syncthreads();
        sh[t] += v;
        __syncthreads();
    }
    if (t < CHN && idx < N_NODES) cursor[idx] = sh[t] - own + co;
}

// scatter emits (orig_edge, src, dst) at the dst-sorted position.
__global__ void scatter_kernel(const int* __restrict__ edge_index, int* __restrict__ cursor,
                               int4* __restrict__ es4)
{
    int e = blockIdx.x * 256 + threadIdx.x;
    if (e < N_EDGES) {
        int src = edge_index[e];
        int dst = edge_index[N_EDGES + e];
        int pos = atomicAdd(&cursor[dst], 1);
        es4[pos] = make_int4(e, src, dst, 0);
    }
}

// ---------------- K5: fused MFMA edge kernel -------------------------------
// Round-4 structure (direct-reg A frags, straight-copy Bf, per-wave kq,
// 1 barrier/tile lockstep) scaled to 512 threads / 8 waves per block:
//  - Bf (We hi+lo, 32KB) amortized over 8 waves.
//  - per-wave kq shrunk 4352->4096B via rotation swizzle col->(col+4*row)&63
//    (keeps pad-68's bank spreading; float4 blocks stay contiguous).
//  - LDS = 32KB + 8*4KB = 65536 -> 2 blocks/CU = 16 waves (was 12).
//  - epilogue-1 r-split: n<8 lanes score r={0,1}, n>=8 score r={2,3}
//    (removes duplicated sqrt path, halves its LDS ops).
__global__ __launch_bounds__(512, 4) void edge_kernel(
    const float* __restrict__ edge_attr,
    const int4*  __restrict__ es4,
    const unsigned short* __restrict__ Bg,
    const float* __restrict__ be,
    const float* __restrict__ Qws, const float* __restrict__ Kws,
    const float* __restrict__ Vws, const float* __restrict__ Aw,
    float* __restrict__ wE,
    float* __restrict__ WVacc, float* __restrict__ RVacc, float* __restrict__ Sacc)
{
    __shared__ __align__(16) unsigned short Bf[16384];   // hi|lo We frags, 32KB
    __shared__ __align__(16) unsigned char  UB[32768];   // 8 x 4096B per-wave kq

    const int t    = threadIdx.x;
    const int lane = t & 63;
    const int w    = t >> 6;
    const int n    = lane & 15;
    const int q    = lane >> 4;
    const int d    = n & 7;
    const int h2   = lane >> 3;
    const int d2l  = lane & 7;

    float* kqw = (float*)(UB + w * 4096);                // 16 x 64 f32, rotated

    // ---- Bf <- Bg: straight 32KB copy, conflict-free ----
    for (int i = 0; i < 4; i++) {
        int o = t + i * 512;                             // 2048 short8 chunks
        *(short8*)&Bf[o * 8] = *(const short8*)&Bg[o * 8];
    }
    float bev[8];
    #pragma unroll
    for (int j = 0; j < 8; j++) bev[j] = be[j * 16 + n];
    const float awv = Aw[d2l * 8 + h2];                  // Aw[d][h]

    for (int it = 0; it < TILES_PER_BLOCK; it++) {
        const int tile  = blockIdx.x + it * EDGE_BLOCKS;
        const int wbase = tile * 128 + w * 16;           // this wave's 16 edges

        __syncthreads();   // lockstep pacing; Bf visible (1st iter)

        // ---- A-frags: direct global loads ----
        int eoA = es4[wbase + (lane & 15)].x;
        const float* arow = &edge_attr[(size_t)eoA * 64 + (lane >> 4) * 8];
        float4 a0 = *(const float4*)&arow[0];
        float4 a1 = *(const float4*)&arow[4];
        float4 a2 = *(const float4*)&arow[32];
        float4 a3 = *(const float4*)&arow[36];

        // ---- stage OWN kq = K[src] + Q[dst] rows (wave-local, rotated) ----
        #pragma unroll
        for (int i = 0; i < 4; i++) {
            int idx = i * 64 + lane;
            int m   = idx >> 4;
            int c4  = (idx & 15) * 4;
            int4 es = es4[wbase + m];
            float4 kv = *(const float4*)&Kws[(size_t)es.y * 64 + c4];
            float4 qv = *(const float4*)&Qws[(size_t)es.z * 64 + c4];
            float4 o;
            o.x = kv.x + qv.x; o.y = kv.y + qv.y; o.z = kv.z + qv.z; o.w = kv.w + qv.w;
            *(float4*)&kqw[m * 64 + ((c4 + 4 * m) & 63)] = o;
        }

        // ---- preload OWN V rows + dsts ----
        float vbuf[16];
        int   dsts[16];
        #pragma unroll
        for (int k = 0; k < 16; k++) {
            int4 es = es4[wbase + k];
            dsts[k] = es.z;
            vbuf[k] = Vws[(size_t)es.y * 64 + lane];
        }

        // ---- hi/lo split of A in registers ----
        float c0[8] = {a0.x, a0.y, a0.z, a0.w, a1.x, a1.y, a1.z, a1.w};
        float c1[8] = {a2.x, a2.y, a2.z, a2.w, a3.x, a3.y, a3.z, a3.w};
        short8 ah0, al0, ah1, al1;
        #pragma unroll
        for (int j = 0; j < 8; j++) {
            unsigned short hi = bf16_rne(c0[j]);
            ah0[j] = (short)hi;
            al0[j] = (short)bf16_rne(c0[j] - bf16_to_f32(hi));
        }
        #pragma unroll
        for (int j = 0; j < 8; j++) {
            unsigned short hi = bf16_rne(c1[j]);
            ah1[j] = (short)hi;
            al1[j] = (short)bf16_rne(c1[j] - bf16_to_f32(hi));
        }

        // ---- MFMA: acc[j] over 8 n-tiles, 2 K-chunks, 3 split products ----
        f32x4 acc[8];
        #pragma unroll
        for (int j = 0; j < 8; j++) acc[j] = (f32x4){0.f, 0.f, 0.f, 0.f};
        #pragma unroll
        for (int j = 0; j < 8; j++) {
            short8 bh0 = *(const short8*)&Bf[(j * 2 + 0) * 512 + lane * 8];
            short8 bh1 = *(const short8*)&Bf[(j * 2 + 1) * 512 + lane * 8];
            short8 bl0 = *(const short8*)&Bf[8192 + (j * 2 + 0) * 512 + lane * 8];
            short8 bl1 = *(const short8*)&Bf[8192 + (j * 2 + 1) * 512 + lane * 8];
            acc[j] = __builtin_amdgcn_mfma_f32_16x16x32_bf16(ah0, bh0, acc[j], 0, 0, 0);
            acc[j] = __builtin_amdgcn_mfma_f32_16x16x32_bf16(ah1, bh1, acc[j], 0, 0, 0);
            acc[j] = __builtin_amdgcn_mfma_f32_16x16x32_bf16(al0, bh0, acc[j], 0, 0, 0);
            acc[j] = __builtin_amdgcn_mfma_f32_16x16x32_bf16(al1, bh1, acc[j], 0, 0, 0);
            acc[j] = __builtin_amdgcn_mfma_f32_16x16x32_bf16(ah0, bl0, acc[j], 0, 0, 0);
            acc[j] = __builtin_amdgcn_mfma_f32_16x16x32_bf16(ah1, bl1, acc[j], 0, 0, 0);
        }

        // ---- epilogue-1 (r-split): scores -> own kq slots ----
        #pragma unroll
        for (int j = 0; j < 8; j++) {
            #pragma unroll
            for (int rr = 0; rr < 2; rr++) {
                float EvA = acc[j][rr]     + bev[j];
                float EvB = acc[j][rr + 2] + bev[j];
                float pvA = __shfl_xor(EvA, 8);
                float pvB = __shfl_xor(EvB, 8);
                int   r  = (n < 8) ? rr  : rr + 2;
                float Ev = (n < 8) ? EvA : EvB;
                float pv = (n < 8) ? pvA : pvB;
                float ew = (n < 8) ? Ev : pv;    // E_w[d]
                float eb = (n < 8) ? pv : Ev;    // E_b[d]
                int el = q * 4 + r;
                int co = ((j * 8 + d) + 4 * el) & 63;
                float kq = kqw[el * 64 + co];
                float v  = kq * ew;
                float sc = copysignf(sqrtf(fabsf(v)), v) + eb;
                sc = fmaxf(sc, 0.0f);
                kqw[el * 64 + co] = sc;
            }
        }
        // scattered wE store at original edge rows (256B/edge, 16 lanes each)
        #pragma unroll
        for (int i = 0; i < 4; i++) {
            int el = i * 4 + q;
            int eo = es4[wbase + el].x;
            float4 o = *(const float4*)&kqw[el * 64 + ((n * 4 + 4 * el) & 63)];
            *(float4*)&wE[(size_t)eo * 64 + n * 4] = o;
        }

        // ---- epilogue-2: segmented accumulate over own 16 sorted edges ----
        float s_acc = 0.f, wvac = 0.f, rvac = 0.f;
        int cur = dsts[0];
        #pragma unroll
        for (int k = 0; k < 16; k++) {
            if (dsts[k] != cur) {                 // wave-uniform branch
                atomicAdd(&WVacc[(size_t)cur * 64 + lane], wvac);
                atomicAdd(&RVacc[(size_t)cur * 64 + lane], rvac);
                if (d2l == 0) atomicAdd(&Sacc[cur * 8 + h2], s_acc);
                s_acc = 0.f; wvac = 0.f; rvac = 0.f;
                cur = dsts[k];
            }
            float sc = kqw[k * 64 + ((lane + 4 * k) & 63)];   // own-wave rows
            float tv = sc * awv;
            tv += __shfl_xor(tv, 1); tv += __shfl_xor(tv, 2); tv += __shfl_xor(tv, 4);
            tv = fminf(fmaxf(tv, -5.0f), 5.0f);
            float ev = __expf(tv);
            s_acc += ev;
            wvac  += ev * vbuf[k];
            rvac  += ev * sc;
        }
        atomicAdd(&WVacc[(size_t)cur * 64 + lane], wvac);
        atomicAdd(&RVacc[(size_t)cur * 64 + lane], rvac);
        if (d2l == 0) atomicAdd(&Sacc[cur * 8 + h2], s_acc);
    }
}

// ---------------- K7: per-node finalize  hout = (wv + VeRow.rv) / s --------
__global__ __launch_bounds__(256) void finalize_kernel(
    const float* __restrict__ WVacc, const float* __restrict__ RVacc,
    const float* __restrict__ Sacc,  const float* __restrict__ VeRow,
    float* __restrict__ hout)
{
    const int t = threadIdx.x;
    const int lane = t & 63;
    const int w = t >> 6;
    const int node = blockIdx.x * 4 + w;
    const int h = lane >> 3, dd = lane & 7;
    float wv = WVacc[(size_t)node * 64 + lane];
    float rv = RVacc[(size_t)node * 64 + lane];
    float s  = Sacc[node * 8 + h];
    float rvt = 0.f;
    int gbase = lane & ~7;
    #pragma unroll
    for (int dk = 0; dk < 8; dk++) {
        float rvd = __shfl(rv, gbase + dk);
        rvt += rvd * VeRow[dk * 64 + h * 8 + dd];
    }
    hout[(size_t)node * 64 + lane] = (wv + rvt) / (s + 1e-16f);
}

// ---------------- launch ----------------------------------------------------
extern "C" void kernel_launch(void* const* d_in, const int* in_sizes, int n_in,
                              void* d_out, int out_size, void* d_ws, size_t ws_size,
                              hipStream_t stream)
{
    const float* x         = (const float*)d_in[0];
    const float* edge_attr = (const float*)d_in[1];
    const int*   edge_index= (const int*)  d_in[2];
    const float* Wq = (const float*)d_in[3];  const float* bq = (const float*)d_in[4];
    const float* Wk = (const float*)d_in[5];  const float* bk = (const float*)d_in[6];
    const float* We = (const float*)d_in[7];  const float* be = (const float*)d_in[8];
    const float* Wv = (const float*)d_in[9];  const float* bv = (const float*)d_in[10];
    const float* Aw = (const float*)d_in[11]; const float* VeRow = (const float*)d_in[12];

    float* hout = (float*)d_out;                       // (N, 64)
    float* wE   = hout + (size_t)N_NODES * 64;         // (E, 64)

    float* Q     = (float*)d_ws;
    float* K     = Q + (size_t)N_NODES * 64;
    float* V     = K + (size_t)N_NODES * 64;
    float* WVacc = V + (size_t)N_NODES * 64;           // (N,64)
    float* RVacc = WVacc + (size_t)N_NODES * 64;       // (N,64)
    float* Sacc  = RVacc + (size_t)N_NODES * 64;       // (N,8)
    int* counts   = (int*)(Sacc + (size_t)N_NODES * 8);
    int* cursor   = counts + N_NODES;
    int* chunksum = cursor + N_NODES;                  // 256
    unsigned short* Bg = (unsigned short*)(chunksum + NCHUNK);     // 16384 us
    int4* es4     = (int4*)(((uintptr_t)(Bg + 16384) + 15) & ~(uintptr_t)15);

    hipMemsetAsync(counts, 0, N_NODES * sizeof(int), stream);
    hipMemsetAsync(WVacc, 0, (size_t)N_NODES * 136 * sizeof(float), stream);  // WV+RV+S
    prep_kernel<<<GEMM_BLOCKS + BPREP_BLOCKS + HIST_BLOCKS, 256, 0, stream>>>(
        x, Wq, bq, Wk, bk, Wv, bv, We, edge_index, Q, K, V, Bg, counts);
    chunk_reduce_kernel<<<NCHUNK, 256, 0, stream>>>(counts, chunksum);
    expand_kernel<<<NCHUNK, 256, 0, stream>>>(counts, chunksum, cursor);
    scatter_kernel<<<(N_EDGES + 255) / 256, 256, 0, stream>>>(edge_index, cursor, es4);
    edge_kernel<<<EDGE_BLOCKS, 512, 0, stream>>>(edge_attr, es4, Bg, be,
                                                 Q, K, V, Aw, wE, WVacc, RVacc, Sacc);
    finalize_kernel<<<N_NODES / 4, 256, 0, stream>>>(WVacc, RVacc, Sacc, VeRow, hout);
}

// Round 6
// 651.520 us; speedup vs baseline: 1.2289x; 1.2289x over previous
//
#include <hip/hip_runtime.h>
#include <math.h>
#include <stdint.h>

#define N_NODES 50000
#define N_EDGES 800000
#define EDGE_BLOCKS 2500
#define TILES_PER_BLOCK 5      // 2500 * 5 * 64 = 800000 edges
#define NCHUNK 256
#define CHN 196                // 256*196 = 50176 >= 50000

#define GEMM_BLOCKS 2346       // 782 * 3
#define BPREP_BLOCKS 8
#define HIST_BLOCKS 3125

typedef __attribute__((ext_vector_type(8))) short short8;   // 8 bf16 (4 VGPRs)
typedef __attribute__((ext_vector_type(4))) float f32x4;

__device__ inline unsigned short bf16_rne(float x) {
    unsigned u = __float_as_uint(x);
    unsigned r = u + 0x7FFFu + ((u >> 16) & 1u);
    return (unsigned short)(r >> 16);
}
__device__ inline float bf16_to_f32(unsigned short h) {
    return __uint_as_float(((unsigned)h) << 16);
}

// packed f32x2 -> bf16x2 (RNE, matches bf16_rne for normal inputs)
__device__ inline unsigned cvtpk(float a, float b) {
    unsigned r;
    asm("v_cvt_pk_bf16_f32 %0, %1, %2" : "=v"(r) : "v"(a), "v"(b));
    return r;
}
__device__ inline float pk_lo_f(unsigned w) { return __uint_as_float(w << 16); }
__device__ inline float pk_hi_f(unsigned w) { return __uint_as_float(w & 0xFFFF0000u); }
__device__ inline short8 pack4(unsigned w0, unsigned w1, unsigned w2, unsigned w3) {
    union { unsigned u[4]; short8 s; } U;
    U.u[0] = w0; U.u[1] = w1; U.u[2] = w2; U.u[3] = w3;
    return U.s;
}

// ---------------- K_A: fused prep  (node GEMM | We-frag prep | dst hist) ---
__global__ __launch_bounds__(256) void prep_kernel(
    const float* __restrict__ x,
    const float* __restrict__ Wq, const float* __restrict__ bq,
    const float* __restrict__ Wk, const float* __restrict__ bk,
    const float* __restrict__ Wv, const float* __restrict__ bv,
    const float* __restrict__ We,
    const int*   __restrict__ edge_index,
    float* __restrict__ Qo, float* __restrict__ Ko, float* __restrict__ Vo,
    unsigned short* __restrict__ Bg, int* __restrict__ counts)
{
    const int b = blockIdx.x;
    const int t = threadIdx.x;

    if (b >= GEMM_BLOCKS + BPREP_BLOCKS) {            // ---- hist ----
        int e = (b - GEMM_BLOCKS - BPREP_BLOCKS) * 256 + t;
        if (e < N_EDGES) atomicAdd(&counts[edge_index[N_EDGES + e]], 1);
        return;
    }
    if (b >= GEMM_BLOCKS) {                           // ---- bprep ----
        int tid = (b - GEMM_BLOCKS) * 256 + t;        // 2048 threads
        int k  = tid >> 5;
        int n4 = (tid & 31) * 4;
        float4 v4 = *(const float4*)&We[(size_t)k * 128 + n4];
        int c = k >> 5, qq = (k >> 3) & 3, jj = k & 7;
        float vv[4] = {v4.x, v4.y, v4.z, v4.w};
        #pragma unroll
        for (int u = 0; u < 4; u++) {
            int nn = n4 + u;
            int j  = nn >> 4;
            int ln = qq * 16 + (nn & 15);
            unsigned short hi = bf16_rne(vv[u]);
            unsigned short lo = bf16_rne(vv[u] - bf16_to_f32(hi));
            Bg[(j * 2 + c) * 512 + ln * 8 + jj] = hi;           // hi half
            Bg[8192 + (j * 2 + c) * 512 + ln * 8 + jj] = lo;    // lo half
        }
        return;
    }

    // ---- node GEMM  X(N x 64) @ W(64 x 64) + b ----
    const int c  = b / 782;
    const int bx = b - c * 782;
    const float* W = (c == 0) ? Wq : (c == 1) ? Wk : Wv;
    const float* bb_ = (c == 0) ? bq : (c == 1) ? bk : bv;
    float* outp    = (c == 0) ? Qo : (c == 1) ? Ko : Vo;

    __shared__ float Xs[64][68];
    __shared__ float Ws[64][64];
    const int n0 = bx * 64;

    for (int i = 0; i < 4; i++) {
        int fi = t + i * 256;
        int row = fi >> 4, c4 = (fi & 15) * 4;
        float4 v = make_float4(0.f, 0.f, 0.f, 0.f);
        if (n0 + row < N_NODES) v = *(const float4*)&x[(size_t)(n0 + row) * 64 + c4];
        *(float4*)&Xs[row][c4] = v;
    }
    for (int i = 0; i < 4; i++) {
        int fi = t + i * 256;
        int row = fi >> 4, c4 = (fi & 15) * 4;
        *(float4*)&Ws[row][c4] = *(const float4*)&W[(size_t)row * 64 + c4];
    }
    __syncthreads();

    const int tx = t & 15, ty = t >> 4;
    float acc[4][4] = {};
    #pragma unroll
    for (int k4 = 0; k4 < 64; k4 += 4) {
        float4 xv[4], wv[4];
        #pragma unroll
        for (int r = 0; r < 4; r++) xv[r] = *(const float4*)&Xs[ty * 4 + r][k4];
        #pragma unroll
        for (int j = 0; j < 4; j++) wv[j] = *(const float4*)&Ws[k4 + j][tx * 4];
        #pragma unroll
        for (int r = 0; r < 4; r++) {
            acc[r][0] += xv[r].x * wv[0].x + xv[r].y * wv[1].x + xv[r].z * wv[2].x + xv[r].w * wv[3].x;
            acc[r][1] += xv[r].x * wv[0].y + xv[r].y * wv[1].y + xv[r].z * wv[2].y + xv[r].w * wv[3].y;
            acc[r][2] += xv[r].x * wv[0].z + xv[r].y * wv[1].z + xv[r].z * wv[2].z + xv[r].w * wv[3].z;
            acc[r][3] += xv[r].x * wv[0].w + xv[r].y * wv[1].w + xv[r].z * wv[2].w + xv[r].w * wv[3].w;
        }
    }
    float4 bv4 = *(const float4*)&bb_[tx * 4];
    #pragma unroll
    for (int r = 0; r < 4; r++) {
        int row = n0 + ty * 4 + r;
        if (row < N_NODES) {
            float4 o;
            o.x = acc[r][0] + bv4.x; o.y = acc[r][1] + bv4.y;
            o.z = acc[r][2] + bv4.z; o.w = acc[r][3] + bv4.w;
            *(float4*)&outp[(size_t)row * 64 + tx * 4] = o;
        }
    }
}

// ---------------- parallel scan (2 kernels) --------------------------------
__global__ __launch_bounds__(256) void chunk_reduce_kernel(
    const int* __restrict__ counts, int* __restrict__ chunksum)
{
    __shared__ int red[256];
    const int c = blockIdx.x, t = threadIdx.x;
    int idx = c * CHN + t;
    int v = (t < CHN && idx < N_NODES) ? counts[idx] : 0;
    red[t] = v;
    __syncthreads();
    for (int s = 128; s > 0; s >>= 1) {
        if (t < s) red[t] += red[t + s];
        __syncthreads();
    }
    if (t == 0) chunksum[c] = red[0];
}

__global__ __launch_bounds__(256) void expand_kernel(
    const int* __restrict__ counts, const int* __restrict__ chunksum,
    int* __restrict__ cursor)
{
    __shared__ int shc[256];
    __shared__ int sh[256];
    const int c = blockIdx.x, t = threadIdx.x;
    shc[t] = chunksum[t];
    __syncthreads();
    for (int off = 1; off < 256; off <<= 1) {
        int v = (t >= off) ? shc[t - off] : 0;
        __syncthreads();
        shc[t] += v;
        __syncthreads();
    }
    int co = (c > 0) ? shc[c - 1] : 0;           // exclusive chunk offset

    int idx = c * CHN + t;
    int own = (t < CHN && idx < N_NODES) ? counts[idx] : 0;
    sh[t] = own;
    __syncthreads();
    for (int off = 1; off < 256; off <<= 1) {
        int v = (t >= off) ? sh[t - off] : 0;
        __syncthreads();
        sh[t] += v;
        __syncthreads();
    }
    if (t < CHN && idx < N_NODES) cursor[idx] = sh[t] - own + co;
}

// scatter emits (orig_edge, src, dst) at the dst-sorted position.
__global__ void scatter_kernel(const int* __restrict__ edge_index, int* __restrict__ cursor,
                               int4* __restrict__ es4)
{
    int e = blockIdx.x * 256 + threadIdx.x;
    if (e < N_EDGES) {
        int src = edge_index[e];
        int dst = edge_index[N_EDGES + e];
        int pos = atomicAdd(&cursor[dst], 1);
        es4[pos] = make_int4(e, src, dst, 0);
    }
}

// ---------------- K5: fused MFMA edge kernel -------------------------------
// Round-4 winner structure (256 thr / 3 blocks/CU, direct-reg A frags,
// straight-copy Bf, per-wave kq stride-68, 1 barrier/tile lockstep) plus:
//  - cvt_pk bf16 hi/lo split (~50 VALU ops vs ~290 for manual RNE)
//  - next-tile A prefetch into regs (issued post-MFMA, hidden under
//    epilogues; bounded 1-tile drift so L2 lockstep locality survives)
//  - r-split epilogue-1 (n<8 lanes do r={0,1}, n>=8 do r={2,3}: halves the
//    sqrt path + its LDS traffic)
__global__ __launch_bounds__(256, 3) void edge_kernel(
    const float* __restrict__ edge_attr,
    const int4*  __restrict__ es4,
    const unsigned short* __restrict__ Bg,
    const float* __restrict__ be,
    const float* __restrict__ Qws, const float* __restrict__ Kws,
    const float* __restrict__ Vws, const float* __restrict__ Aw,
    float* __restrict__ wE,
    float* __restrict__ WVacc, float* __restrict__ RVacc, float* __restrict__ Sacc)
{
    __shared__ __align__(16) unsigned short Bf[16384];   // hi|lo We frags, 32KB
    __shared__ __align__(16) unsigned char  UB[17408];   // 4 x 4352B per-wave kq

    const int t    = threadIdx.x;
    const int lane = t & 63;
    const int w    = t >> 6;
    const int n    = lane & 15;
    const int q    = lane >> 4;
    const int d    = n & 7;
    const int h2   = lane >> 3;
    const int d2l  = lane & 7;

    float* kqw = (float*)(UB + w * 4352);                // 16 x 68 f32

    // ---- Bf <- Bg: straight 32KB copy, conflict-free ----
    for (int i = 0; i < 8; i++) {
        int o = t + i * 256;                             // 2048 short8 chunks
        *(short8*)&Bf[o * 8] = *(const short8*)&Bg[o * 8];
    }
    float bev[8];
    #pragma unroll
    for (int j = 0; j < 8; j++) bev[j] = be[j * 16 + n];
    const float awv = Aw[d2l * 8 + h2];                  // Aw[d][h]

    // ---- prefetch tile 0's A rows into regs ----
    {
        int wb0 = blockIdx.x * 64 + w * 16;
        int eoA = es4[wb0 + (lane & 15)].x;
        const float* arow = &edge_attr[(size_t)eoA * 64 + (lane >> 4) * 8];
        // loads issued here; consumed after first barrier
        // (a0..a3 declared below, assigned here via pointer loads)
    }
    float4 a0, a1, a2, a3;
    {
        int wb0 = blockIdx.x * 64 + w * 16;
        int eoA = es4[wb0 + (lane & 15)].x;
        const float* arow = &edge_attr[(size_t)eoA * 64 + (lane >> 4) * 8];
        a0 = *(const float4*)&arow[0];
        a1 = *(const float4*)&arow[4];
        a2 = *(const float4*)&arow[32];
        a3 = *(const float4*)&arow[36];
    }

    for (int it = 0; it < TILES_PER_BLOCK; it++) {
        const int tile  = blockIdx.x + it * EDGE_BLOCKS;
        const int wbase = tile * 64 + w * 16;            // this wave's 16 edges

        __syncthreads();   // lockstep pacing; Bf visible (1st iter)

        // ---- stage OWN kq = K[src] + Q[dst] rows (wave-local) ----
        #pragma unroll
        for (int i = 0; i < 4; i++) {
            int idx = i * 64 + lane;
            int m   = idx >> 4;
            int c4  = (idx & 15) * 4;
            int4 es = es4[wbase + m];
            float4 kv = *(const float4*)&Kws[(size_t)es.y * 64 + c4];
            float4 qv = *(const float4*)&Qws[(size_t)es.z * 64 + c4];
            float4 o;
            o.x = kv.x + qv.x; o.y = kv.y + qv.y; o.z = kv.z + qv.z; o.w = kv.w + qv.w;
            *(float4*)&kqw[m * 68 + c4] = o;
        }

        // ---- preload OWN V rows + dsts ----
        float vbuf[16];
        int   dsts[16];
        #pragma unroll
        for (int k = 0; k < 16; k++) {
            int4 es = es4[wbase + k];
            dsts[k] = es.z;
            vbuf[k] = Vws[(size_t)es.y * 64 + lane];
        }

        // ---- hi/lo split of A via packed converts ----
        short8 ah0, al0, ah1, al1;
        {
            unsigned h0 = cvtpk(a0.x, a0.y), h1 = cvtpk(a0.z, a0.w);
            unsigned h2_ = cvtpk(a1.x, a1.y), h3 = cvtpk(a1.z, a1.w);
            unsigned l0 = cvtpk(a0.x - pk_lo_f(h0), a0.y - pk_hi_f(h0));
            unsigned l1 = cvtpk(a0.z - pk_lo_f(h1), a0.w - pk_hi_f(h1));
            unsigned l2 = cvtpk(a1.x - pk_lo_f(h2_), a1.y - pk_hi_f(h2_));
            unsigned l3 = cvtpk(a1.z - pk_lo_f(h3), a1.w - pk_hi_f(h3));
            ah0 = pack4(h0, h1, h2_, h3);
            al0 = pack4(l0, l1, l2, l3);
        }
        {
            unsigned h0 = cvtpk(a2.x, a2.y), h1 = cvtpk(a2.z, a2.w);
            unsigned h2_ = cvtpk(a3.x, a3.y), h3 = cvtpk(a3.z, a3.w);
            unsigned l0 = cvtpk(a2.x - pk_lo_f(h0), a2.y - pk_hi_f(h0));
            unsigned l1 = cvtpk(a2.z - pk_lo_f(h1), a2.w - pk_hi_f(h1));
            unsigned l2 = cvtpk(a3.x - pk_lo_f(h2_), a3.y - pk_hi_f(h2_));
            unsigned l3 = cvtpk(a3.z - pk_lo_f(h3), a3.w - pk_hi_f(h3));
            ah1 = pack4(h0, h1, h2_, h3);
            al1 = pack4(l0, l1, l2, l3);
        }

        // ---- MFMA: acc[j] over 8 n-tiles, 2 K-chunks, 3 split products ----
        f32x4 acc[8];
        #pragma unroll
        for (int j = 0; j < 8; j++) acc[j] = (f32x4){0.f, 0.f, 0.f, 0.f};
        #pragma unroll
        for (int j = 0; j < 8; j++) {
            short8 bh0 = *(const short8*)&Bf[(j * 2 + 0) * 512 + lane * 8];
            short8 bh1 = *(const short8*)&Bf[(j * 2 + 1) * 512 + lane * 8];
            short8 bl0 = *(const short8*)&Bf[8192 + (j * 2 + 0) * 512 + lane * 8];
            short8 bl1 = *(const short8*)&Bf[8192 + (j * 2 + 1) * 512 + lane * 8];
            acc[j] = __builtin_amdgcn_mfma_f32_16x16x32_bf16(ah0, bh0, acc[j], 0, 0, 0);
            acc[j] = __builtin_amdgcn_mfma_f32_16x16x32_bf16(ah1, bh1, acc[j], 0, 0, 0);
            acc[j] = __builtin_amdgcn_mfma_f32_16x16x32_bf16(al0, bh0, acc[j], 0, 0, 0);
            acc[j] = __builtin_amdgcn_mfma_f32_16x16x32_bf16(al1, bh1, acc[j], 0, 0, 0);
            acc[j] = __builtin_amdgcn_mfma_f32_16x16x32_bf16(ah0, bl0, acc[j], 0, 0, 0);
            acc[j] = __builtin_amdgcn_mfma_f32_16x16x32_bf16(ah1, bl1, acc[j], 0, 0, 0);
        }

        // ---- prefetch NEXT tile's A rows (hidden under epilogues) ----
        {
            int tn  = (it + 1 < TILES_PER_BLOCK) ? tile + EDGE_BLOCKS : tile;
            int wbn = tn * 64 + w * 16;
            int eoN = es4[wbn + (lane & 15)].x;
            const float* arn = &edge_attr[(size_t)eoN * 64 + (lane >> 4) * 8];
            a0 = *(const float4*)&arn[0];
            a1 = *(const float4*)&arn[4];
            a2 = *(const float4*)&arn[32];
            a3 = *(const float4*)&arn[36];
        }

        // ---- epilogue-1 (r-split): scores -> own kq slots ----
        #pragma unroll
        for (int j = 0; j < 8; j++) {
            #pragma unroll
            for (int rr = 0; rr < 2; rr++) {
                float EvA = acc[j][rr]     + bev[j];
                float EvB = acc[j][rr + 2] + bev[j];
                float pvA = __shfl_xor(EvA, 8);
                float pvB = __shfl_xor(EvB, 8);
                int   r  = (n < 8) ? rr  : rr + 2;
                float Ev = (n < 8) ? EvA : EvB;
                float pv = (n < 8) ? pvA : pvB;
                float ew = (n < 8) ? Ev : pv;    // E_w[d]
                float eb = (n < 8) ? pv : Ev;    // E_b[d]
                int el = q * 4 + r;
                float kq = kqw[el * 68 + j * 8 + d];
                float v  = kq * ew;
                float sc = copysignf(sqrtf(fabsf(v)), v) + eb;
                sc = fmaxf(sc, 0.0f);
                kqw[el * 68 + j * 8 + d] = sc;
            }
        }
        // scattered wE store at original edge rows (256B/edge, 16 lanes each)
        #pragma unroll
        for (int i = 0; i < 4; i++) {
            int el = i * 4 + q;
            int eo = es4[wbase + el].x;
            float4 o = *(const float4*)&kqw[el * 68 + n * 4];
            *(float4*)&wE[(size_t)eo * 64 + n * 4] = o;
        }

        // ---- epilogue-2: segmented accumulate over own 16 sorted edges ----
        float s_acc = 0.f, wvac = 0.f, rvac = 0.f;
        int cur = dsts[0];
        #pragma unroll
        for (int k = 0; k < 16; k++) {
            if (dsts[k] != cur) {                 // wave-uniform branch
                atomicAdd(&WVacc[(size_t)cur * 64 + lane], wvac);
                atomicAdd(&RVacc[(size_t)cur * 64 + lane], rvac);
                if (d2l == 0) atomicAdd(&Sacc[cur * 8 + h2], s_acc);
                s_acc = 0.f; wvac = 0.f; rvac = 0.f;
                cur = dsts[k];
            }
            float sc = kqw[k * 68 + lane];        // own-wave rows
            float tv = sc * awv;
            tv += __shfl_xor(tv, 1); tv += __shfl_xor(tv, 2); tv += __shfl_xor(tv, 4);
            tv = fminf(fmaxf(tv, -5.0f), 5.0f);
            float ev = __expf(tv);
            s_acc += ev;
            wvac  += ev * vbuf[k];
            rvac  += ev * sc;
        }
        atomicAdd(&WVacc[(size_t)cur * 64 + lane], wvac);
        atomicAdd(&RVacc[(size_t)cur * 64 + lane], rvac);
        if (d2l == 0) atomicAdd(&Sacc[cur * 8 + h2], s_acc);
    }
}

// ---------------- K7: per-node finalize  hout = (wv + VeRow.rv) / s --------
__global__ __launch_bounds__(256) void finalize_kernel(
    const float* __restrict__ WVacc, const float* __restrict__ RVacc,
    const float* __restrict__ Sacc,  const float* __restrict__ VeRow,
    float* __restrict__ hout)
{
    const int t = threadIdx.x;
    const int lane = t & 63;
    const int w = t >> 6;
    const int node = blockIdx.x * 4 + w;
    const int h = lane >> 3, dd = lane & 7;
    float wv = WVacc[(size_t)node * 64 + lane];
    float rv = RVacc[(size_t)node * 64 + lane];
    float s  = Sacc[node * 8 + h];
    float rvt = 0.f;
    int gbase = lane & ~7;
    #pragma unroll
    for (int dk = 0; dk < 8; dk++) {
        float rvd = __shfl(rv, gbase + dk);
        rvt += rvd * VeRow[dk * 64 + h * 8 + dd];
    }
    hout[(size_t)node * 64 + lane] = (wv + rvt) / (s + 1e-16f);
}

// ---------------- launch ----------------------------------------------------
extern "C" void kernel_launch(void* const* d_in, const int* in_sizes, int n_in,
                              void* d_out, int out_size, void* d_ws, size_t ws_size,
                              hipStream_t stream)
{
    const float* x         = (const float*)d_in[0];
    const float* edge_attr = (const float*)d_in[1];
    const int*   edge_index= (const int*)  d_in[2];
    const float* Wq = (const float*)d_in[3];  const float* bq = (const float*)d_in[4];
    const float* Wk = (const float*)d_in[5];  const float* bk = (const float*)d_in[6];
    const float* We = (const float*)d_in[7];  const float* be = (const float*)d_in[8];
    const float* Wv = (const float*)d_in[9];  const float* bv = (const float*)d_in[10];
    const float* Aw = (const float*)d_in[11]; const float* VeRow = (const float*)d_in[12];

    float* hout = (float*)d_out;                       // (N, 64)
    float* wE   = hout + (size_t)N_NODES * 64;         // (E, 64)

    float* Q     = (float*)d_ws;
    float* K     = Q + (size_t)N_NODES * 64;
    float* V     = K + (size_t)N_NODES * 64;
    float* WVacc = V + (size_t)N_NODES * 64;           // (N,64)
    float* RVacc = WVacc + (size_t)N_NODES * 64;       // (N,64)
    float* Sacc  = RVacc + (size_t)N_NODES * 64;       // (N,8)
    int* counts   = (int*)(Sacc + (size_t)N_NODES * 8);
    int* cursor   = counts + N_NODES;
    int* chunksum = cursor + N_NODES;                  // 256
    unsigned short* Bg = (unsigned short*)(chunksum + NCHUNK);     // 16384 us
    int4* es4     = (int4*)(((uintptr_t)(Bg + 16384) + 15) & ~(uintptr_t)15);

    hipMemsetAsync(counts, 0, N_NODES * sizeof(int), stream);
    hipMemsetAsync(WVacc, 0, (size_t)N_NODES * 136 * sizeof(float), stream);  // WV+RV+S
    prep_kernel<<<GEMM_BLOCKS + BPREP_BLOCKS + HIST_BLOCKS, 256, 0, stream>>>(
        x, Wq, bq, Wk, bk, Wv, bv, We, edge_index, Q, K, V, Bg, counts);
    chunk_reduce_kernel<<<NCHUNK, 256, 0, stream>>>(counts, chunksum);
    expand_kernel<<<NCHUNK, 256, 0, stream>>>(counts, chunksum, cursor);
    scatter_kernel<<<(N_EDGES + 255) / 256, 256, 0, stream>>>(edge_index, cursor, es4);
    edge_kernel<<<EDGE_BLOCKS, 256, 0, stream>>>(edge_attr, es4, Bg, be,
                                                 Q, K, V, Aw, wE, WVacc, RVacc, Sacc);
    finalize_kernel<<<N_NODES / 4, 256, 0, stream>>>(WVacc, RVacc, Sacc, VeRow, hout);
}